// Round 4
// baseline (129.699 us; speedup 1.0000x reference)
//
#include <hip/hip_runtime.h>
#include <hip/hip_cooperative_groups.h>
#include <float.h>
#include <math.h>

namespace cg = cooperative_groups;

#define B 128
#define D 128
#define N 3072      // 3*32*32
#define NP 4096     // next pow2 for bitonic sort
#define NPAIR (B*(B+1)/2)   // 8256 upper-triangular pairs (i<=j)
#define GRID 256    // 1 block/CU, cooperative

// ---------------------------------------------------------------------------
// One cooperative kernel, two phases separated by grid.sync():
//  phase 1: blocks 0..127 bitonic-sort x rows into xs (validated R2 logic);
//           blocks 128..143 compute zcos with inline L2-normalize (validated R3);
//           block 144 zeroes the atomicAdd target.
//  phase 2: all 256 blocks x 16 waves sweep the 8256 upper-tri pairs
//           (EMD + weighted sq-err), one atomicAdd per block.
// grid.sync() provides the device-scope fence for cross-XCD visibility of
// xs/zcos (G16).
// ---------------------------------------------------------------------------
__global__ __launch_bounds__(1024) void fused_kernel(const float* __restrict__ x,
                                                     const float* __restrict__ z,
                                                     float* __restrict__ xs,
                                                     float* __restrict__ zcos,
                                                     float* __restrict__ out) {
    cg::grid_group grid = cg::this_grid();
    __shared__ float smem[NP];         // sort buffer / z inv-norms (phase 1)
    __shared__ float mx[2];
    __shared__ float partial[16];
    int tid = threadIdx.x;
    int bid = blockIdx.x;

    // ---------------- phase 1 ----------------
    if (bid < B) {
        // ----- sort role (validated round 2/3, verbatim logic) -----
        float* buf = smem;
        int row = bid;
        const float4* xr = (const float4*)(x + (size_t)row * N);
        if (tid < N / 4)
            ((float4*)buf)[tid] = xr[tid];
        else
            ((float4*)buf)[tid] = make_float4(FLT_MAX, FLT_MAX, FLT_MAX, FLT_MAX);
        __syncthreads();

        for (int k = 2; k <= NP; k <<= 1) {
            for (int j = k >> 1; j > 0; j >>= 1) {
                #pragma unroll
                for (int u = 0; u < 2; u++) {
                    int p = tid + u * 1024;        // pair index in [0, 2048)
                    int i = ((p & ~(j - 1)) << 1) | (p & (j - 1));
                    int pj = i | j;
                    float a = buf[i];
                    float b = buf[pj];
                    bool up = ((i & k) == 0);
                    if ((a > b) == up) { buf[i] = b; buf[pj] = a; }
                }
                __syncthreads();
            }
        }

        if (tid < N / 4)
            ((float4*)(xs + (size_t)row * N))[tid] = ((float4*)buf)[tid];
    } else if (bid < B + 16) {
        // ----- z role: 8 rows of zcos per block (validated round 3) -----
        float* inv_s = smem;           // [128] inverse norms
        {
            int row = tid >> 3;        // 0..127
            int seg = tid & 7;
            const float4* zr = (const float4*)(z + row * D + seg * 16);
            float s = 0.f;
            #pragma unroll
            for (int u = 0; u < 4; u++) {
                float4 v = zr[u];
                s += v.x * v.x + v.y * v.y + v.z * v.z + v.w * v.w;
            }
            s += __shfl_down(s, 4, 8);
            s += __shfl_down(s, 2, 8);
            s += __shfl_down(s, 1, 8);
            if (seg == 0) inv_s[row] = 1.0f / fmaxf(sqrtf(s), 1e-12f);
        }
        __syncthreads();

        int gi = (bid - B) * 8 + (tid >> 7);      // global row i
        int j  = tid & 127;
        const float4* zi = (const float4*)(z + gi * D);
        const float4* zj = (const float4*)(z + j * D);
        float dot = 0.f;
        #pragma unroll 8
        for (int k4 = 0; k4 < D / 4; k4++) {
            float4 a = zi[k4], b = zj[k4];
            dot += a.x * b.x + a.y * b.y + a.z * b.z + a.w * b.w;
        }
        zcos[gi * B + j] = dot * inv_s[gi] * inv_s[j];
    } else if (bid == B + 16 && tid == 0) {
        out[0] = 0.f;                  // zero the atomicAdd target
    }

    grid.sync();

    // ---------------- phase 2: pairs ----------------
    // per-block diagonal max of zcos (max(z_cos) is attained on the diagonal)
    if (tid < B) {
        float v = zcos[tid * (B + 1)];
        #pragma unroll
        for (int o = 32; o > 0; o >>= 1) v = fmaxf(v, __shfl_down(v, o, 64));
        if ((tid & 63) == 0) mx[tid >> 6] = v;
    }
    __syncthreads();
    float maxv = fmaxf(mx[0], mx[1]);

    int w = tid >> 6;                  // wave 0..15
    int lane = tid & 63;
    float wsum = 0.f;                  // valid on lane 0 only

    for (int t = bid * 16 + w; t < NPAIR; t += GRID * 16) {
        // decode t -> (i, j), i<=j ; start(i) = i*B - i*(i-1)/2  (validated R2)
        float ff = (float)(2 * B + 1);
        int i = (int)((ff - sqrtf(ff * ff - 8.0f * (float)t)) * 0.5f);
        if (i < 0) i = 0;
        if (i > B - 1) i = B - 1;
        while ((i + 1) * B - ((i + 1) * i) / 2 <= t) i++;
        while (i * B - (i * (i - 1)) / 2 > t) i--;
        int j = i + (t - (i * B - (i * (i - 1)) / 2));

        const float4* a = (const float4*)(xs + (size_t)i * N);
        const float4* b = (const float4*)(xs + (size_t)j * N);
        float s = 0.f;
        #pragma unroll
        for (int u = 0; u < N / 4 / 64; u++) {      // 12 iterations
            int idx = lane + u * 64;
            float4 va = a[idx], vb = b[idx];
            s += fabsf(va.x - vb.x) + fabsf(va.y - vb.y)
               + fabsf(va.z - vb.z) + fabsf(va.w - vb.w);
        }
        #pragma unroll
        for (int o = 32; o > 0; o >>= 1) s += __shfl_down(s, o, 64);
        if (lane == 0) {
            float emd = s * (1.0f / N);
            float cosd = maxv - zcos[i * B + j];
            float d = emd - cosd;
            float wgt = (i == j) ? 1.0f : 2.0f;
            wsum += wgt * d * d;
        }
    }

    if (lane == 0) partial[w] = wsum;
    __syncthreads();
    if (tid == 0) {
        float blk = 0.f;
        #pragma unroll
        for (int u = 0; u < 16; u++) blk += partial[u];
        atomicAdd(out, blk * (1.0f / (B * B)));
    }
}

extern "C" void kernel_launch(void* const* d_in, const int* in_sizes, int n_in,
                              void* d_out, int out_size, void* d_ws, size_t ws_size,
                              hipStream_t stream) {
    const float* z = (const float*)d_in[0];   // [128,128]
    const float* x = (const float*)d_in[1];   // [128,3,32,32]
    float* out = (float*)d_out;               // [1]
    float* ws = (float*)d_ws;

    float* zcos = ws;                         // 16384 floats
    float* xs   = ws + 16384;                 // 393216 floats

    void* args[] = { (void*)&x, (void*)&z, (void*)&xs, (void*)&zcos, (void*)&out };
    hipLaunchCooperativeKernel((const void*)fused_kernel, dim3(GRID), dim3(1024),
                               args, 0, stream);
}

// Round 5
// 90.765 us; speedup vs baseline: 1.4289x; 1.4289x over previous
//
#include <hip/hip_runtime.h>
#include <float.h>
#include <math.h>

#define B 128
#define D 128
#define N 3072      // 3*32*32
#define NP 4096     // next pow2 for bitonic sort
#define NPAIR (B*(B+1)/2)   // 8256 upper-triangular pairs (i<=j)
#define NZBLK 16            // z-role blocks (each does 8 rows of zcos)

__device__ __forceinline__ void cas(float& a, float& b, bool up) {
    // a is the LOWER-index element of the pair
    float lo = fminf(a, b), hi = fmaxf(a, b);
    a = up ? lo : hi;
    b = up ? hi : lo;
}

// ---------------------------------------------------------------------------
// K1 prep: blocks 0..127  : register/shfl bitonic sort of row b of x -> xs
//          blocks 128..143: zcos rows with inline L2-normalize (validated R3/R4)
//          block 144      : zero the atomicAdd target
//
// Sort mapping: element idx = 4*tid + r  (thread tid holds v[0..3]).
//   j in {1,2}   -> in-thread register CAS           (23 passes, free)
//   j in {4..128}-> __shfl_xor lane CAS, lx = j>>2   (45 passes, no barrier)
//   j >= 256     -> LDS pair-formulation CAS         (10 passes, stride-1 =
//                   conflict-free), registers dumped/reloaded per k-section.
// Direction: up = ((idx & k)==0); for k>=4 uniform over r (base=4t | r, no carry).
// ---------------------------------------------------------------------------
__global__ __launch_bounds__(1024) void prep_kernel(const float* __restrict__ x,
                                                    const float* __restrict__ z,
                                                    float* __restrict__ xs,
                                                    float* __restrict__ zcos,
                                                    float* __restrict__ out) {
    __shared__ float smem[NP];         // sort buffer / z inv-norms
    int tid = threadIdx.x;
    int bid = blockIdx.x;

    if (bid < B) {
        float* buf = smem;
        int row = bid;
        int base = tid * 4;
        float v[4];

        // coalesced float4 load; pad tail with +FLT_MAX
        if (base < N) {
            float4 t4 = ((const float4*)(x + (size_t)row * N))[tid];
            v[0] = t4.x; v[1] = t4.y; v[2] = t4.z; v[3] = t4.w;
        } else {
            v[0] = v[1] = v[2] = v[3] = FLT_MAX;
        }

        for (int k = 2; k <= NP; k <<= 1) {
            int j = k >> 1;
            bool ub = ((base & k) == 0);           // direction, uniform for k>=4

            if (j >= 256) {
                // dump registers -> LDS (stride-1 b128, conflict-free)
                ((float4*)buf)[tid] = make_float4(v[0], v[1], v[2], v[3]);
                __syncthreads();
                for (; j >= 256; j >>= 1) {
                    #pragma unroll
                    for (int u = 0; u < 2; u++) {
                        int p = tid + u * 1024;    // pair index in [0,2048)
                        int i = ((p & ~(j - 1)) << 1) | (p & (j - 1));
                        int pj = i | j;
                        float a = buf[i], b2 = buf[pj];
                        bool up = ((i & k) == 0);
                        if ((a > b2) == up) { buf[i] = b2; buf[pj] = a; }
                    }
                    __syncthreads();
                }
                float4 t4 = ((float4*)buf)[tid];
                v[0] = t4.x; v[1] = t4.y; v[2] = t4.z; v[3] = t4.w;
                __syncthreads();                    // protect buf before next dump
            }

            for (; j >= 4; j >>= 1) {              // lane-exchange passes
                int lx = j >> 2;
                bool keep_lower = ((tid & lx) == 0);
                bool sel = (keep_lower == ub);
                #pragma unroll
                for (int r = 0; r < 4; r++) {
                    float p = __shfl_xor(v[r], lx, 64);
                    v[r] = sel ? fminf(v[r], p) : fmaxf(v[r], p);
                }
            }
            if (j == 2) {                          // register pairs (0,2),(1,3)
                cas(v[0], v[2], ub);
                cas(v[1], v[3], ub);
                j >>= 1;
            }
            // j == 1: register pairs (0,1),(2,3); k==2 needs per-pair direction
            {
                bool upA = (((base + 0) & k) == 0);
                bool upB = (((base + 2) & k) == 0);
                cas(v[0], v[1], upA);
                cas(v[2], v[3], upB);
            }
        }

        if (base < N)
            ((float4*)(xs + (size_t)row * N))[tid] = make_float4(v[0], v[1], v[2], v[3]);
    } else if (bid < B + NZBLK) {
        // ----- z role: 8 rows of zcos per block (validated R3/R4) -----
        float* inv_s = smem;           // [128] inverse norms
        {
            int row = tid >> 3;        // 0..127
            int seg = tid & 7;
            const float4* zr = (const float4*)(z + row * D + seg * 16);
            float s = 0.f;
            #pragma unroll
            for (int u = 0; u < 4; u++) {
                float4 v = zr[u];
                s += v.x * v.x + v.y * v.y + v.z * v.z + v.w * v.w;
            }
            s += __shfl_down(s, 4, 8);
            s += __shfl_down(s, 2, 8);
            s += __shfl_down(s, 1, 8);
            if (seg == 0) inv_s[row] = 1.0f / fmaxf(sqrtf(s), 1e-12f);
        }
        __syncthreads();

        int gi = (bid - B) * 8 + (tid >> 7);      // global row i
        int j  = tid & 127;
        const float4* zi = (const float4*)(z + gi * D);
        const float4* zj = (const float4*)(z + j * D);
        float dot = 0.f;
        #pragma unroll 8
        for (int k4 = 0; k4 < D / 4; k4++) {
            float4 a = zi[k4], b = zj[k4];
            dot += a.x * b.x + a.y * b.y + a.z * b.z + a.w * b.w;
        }
        zcos[gi * B + j] = dot * inv_s[gi] * inv_s[j];
    } else if (tid == 0) {
        out[0] = 0.f;                  // zero the atomicAdd target
    }
}

// ---------------------------------------------------------------------------
// K2 pair (validated R3): 516 blocks x 16 waves, one upper-tri pair per wave.
// Per-block diag-max of zcos (max attained on diagonal); atomicAdd per block.
// ---------------------------------------------------------------------------
__global__ __launch_bounds__(1024) void pair_kernel(const float* __restrict__ xs,
                                                    const float* __restrict__ zcos,
                                                    float* __restrict__ out) {
    __shared__ float mx[2];
    __shared__ float partial[16];
    int tid = threadIdx.x;

    if (tid < B) {
        float v = zcos[tid * (B + 1)];
        #pragma unroll
        for (int o = 32; o > 0; o >>= 1) v = fmaxf(v, __shfl_down(v, o, 64));
        if ((tid & 63) == 0) mx[tid >> 6] = v;
    }
    __syncthreads();
    float maxv = fmaxf(mx[0], mx[1]);

    int w = tid >> 6;                  // wave 0..15
    int lane = tid & 63;
    int t = blockIdx.x * 16 + w;       // triangular pair index (516*16 == 8256)

    // decode t -> (i, j), i<=j ; start(i) = i*B - i*(i-1)/2  (validated R2)
    float ff = (float)(2 * B + 1);
    int i = (int)((ff - sqrtf(ff * ff - 8.0f * (float)t)) * 0.5f);
    if (i < 0) i = 0;
    if (i > B - 1) i = B - 1;
    while ((i + 1) * B - ((i + 1) * i) / 2 <= t) i++;
    while (i * B - (i * (i - 1)) / 2 > t) i--;
    int j = i + (t - (i * B - (i * (i - 1)) / 2));

    const float4* a = (const float4*)(xs + (size_t)i * N);
    const float4* b = (const float4*)(xs + (size_t)j * N);
    float s = 0.f;
    #pragma unroll
    for (int u = 0; u < N / 4 / 64; u++) {          // 12 iterations
        int idx = lane + u * 64;
        float4 va = a[idx], vb = b[idx];
        s += fabsf(va.x - vb.x) + fabsf(va.y - vb.y)
           + fabsf(va.z - vb.z) + fabsf(va.w - vb.w);
    }
    #pragma unroll
    for (int o = 32; o > 0; o >>= 1) s += __shfl_down(s, o, 64);
    if (lane == 0) {
        float emd = s * (1.0f / N);
        float cosd = maxv - zcos[i * B + j];
        float d = emd - cosd;
        float wgt = (i == j) ? 1.0f : 2.0f;
        partial[w] = wgt * d * d;
    }
    __syncthreads();
    if (tid == 0) {
        float blk = 0.f;
        #pragma unroll
        for (int u = 0; u < 16; u++) blk += partial[u];
        atomicAdd(out, blk * (1.0f / (B * B)));
    }
}

extern "C" void kernel_launch(void* const* d_in, const int* in_sizes, int n_in,
                              void* d_out, int out_size, void* d_ws, size_t ws_size,
                              hipStream_t stream) {
    const float* z = (const float*)d_in[0];   // [128,128]
    const float* x = (const float*)d_in[1];   // [128,3,32,32]
    float* out = (float*)d_out;               // [1]
    float* ws = (float*)d_ws;

    float* zcos = ws;                         // 16384 floats
    float* xs   = ws + 16384;                 // 393216 floats

    prep_kernel<<<B + NZBLK + 1, 1024, 0, stream>>>(x, z, xs, zcos, out);
    pair_kernel<<<NPAIR / 16, 1024, 0, stream>>>(xs, zcos, out);
}

// Round 6
// 88.004 us; speedup vs baseline: 1.4738x; 1.0314x over previous
//
#include <hip/hip_runtime.h>
#include <float.h>
#include <math.h>

#define B 128
#define D 128
#define N 3072      // 3*32*32
#define NP 4096     // next pow2 for bitonic sort
#define NZBLK 16    // z-role blocks (each does 8 rows of zcos)
#define TROW 64     // row-tiles (2 rows each)
#define NTILE (TROW*(TROW+1)/2)   // 2080 upper-tri 2x2 tiles
#define PAIR_BLOCKS (NTILE/4)     // 520 blocks x 4 waves, exact

__device__ __forceinline__ void cas(float& a, float& b, bool up) {
    float lo = fminf(a, b), hi = fmaxf(a, b);
    a = up ? lo : hi;
    b = up ? hi : lo;
}

// ---------------------------------------------------------------------------
// K1 prep (validated R5): blocks 0..127 register/shfl bitonic sort of x rows;
// blocks 128..143 zcos with inline L2-normalize; block 144 zeroes out[0].
// ---------------------------------------------------------------------------
__global__ __launch_bounds__(1024) void prep_kernel(const float* __restrict__ x,
                                                    const float* __restrict__ z,
                                                    float* __restrict__ xs,
                                                    float* __restrict__ zcos,
                                                    float* __restrict__ out) {
    __shared__ float smem[NP];
    int tid = threadIdx.x;
    int bid = blockIdx.x;

    if (bid < B) {
        float* buf = smem;
        int row = bid;
        int base = tid * 4;
        float v[4];

        if (base < N) {
            float4 t4 = ((const float4*)(x + (size_t)row * N))[tid];
            v[0] = t4.x; v[1] = t4.y; v[2] = t4.z; v[3] = t4.w;
        } else {
            v[0] = v[1] = v[2] = v[3] = FLT_MAX;
        }

        for (int k = 2; k <= NP; k <<= 1) {
            int j = k >> 1;
            bool ub = ((base & k) == 0);

            if (j >= 256) {
                ((float4*)buf)[tid] = make_float4(v[0], v[1], v[2], v[3]);
                __syncthreads();
                for (; j >= 256; j >>= 1) {
                    #pragma unroll
                    for (int u = 0; u < 2; u++) {
                        int p = tid + u * 1024;
                        int i = ((p & ~(j - 1)) << 1) | (p & (j - 1));
                        int pj = i | j;
                        float a = buf[i], b2 = buf[pj];
                        bool up = ((i & k) == 0);
                        if ((a > b2) == up) { buf[i] = b2; buf[pj] = a; }
                    }
                    __syncthreads();
                }
                float4 t4 = ((float4*)buf)[tid];
                v[0] = t4.x; v[1] = t4.y; v[2] = t4.z; v[3] = t4.w;
                __syncthreads();
            }

            for (; j >= 4; j >>= 1) {
                int lx = j >> 2;
                bool keep_lower = ((tid & lx) == 0);
                bool sel = (keep_lower == ub);
                #pragma unroll
                for (int r = 0; r < 4; r++) {
                    float p = __shfl_xor(v[r], lx, 64);
                    v[r] = sel ? fminf(v[r], p) : fmaxf(v[r], p);
                }
            }
            if (j == 2) {
                cas(v[0], v[2], ub);
                cas(v[1], v[3], ub);
                j >>= 1;
            }
            {
                bool upA = (((base + 0) & k) == 0);
                bool upB = (((base + 2) & k) == 0);
                cas(v[0], v[1], upA);
                cas(v[2], v[3], upB);
            }
        }

        if (base < N)
            ((float4*)(xs + (size_t)row * N))[tid] = make_float4(v[0], v[1], v[2], v[3]);
    } else if (bid < B + NZBLK) {
        float* inv_s = smem;           // [128] inverse norms
        {
            int row = tid >> 3;
            int seg = tid & 7;
            const float4* zr = (const float4*)(z + row * D + seg * 16);
            float s = 0.f;
            #pragma unroll
            for (int u = 0; u < 4; u++) {
                float4 v = zr[u];
                s += v.x * v.x + v.y * v.y + v.z * v.z + v.w * v.w;
            }
            s += __shfl_down(s, 4, 8);
            s += __shfl_down(s, 2, 8);
            s += __shfl_down(s, 1, 8);
            if (seg == 0) inv_s[row] = 1.0f / fmaxf(sqrtf(s), 1e-12f);
        }
        __syncthreads();

        int gi = (bid - B) * 8 + (tid >> 7);
        int j  = tid & 127;
        const float4* zi = (const float4*)(z + gi * D);
        const float4* zj = (const float4*)(z + j * D);
        float dot = 0.f;
        #pragma unroll 8
        for (int k4 = 0; k4 < D / 4; k4++) {
            float4 a = zi[k4], b = zj[k4];
            dot += a.x * b.x + a.y * b.y + a.z * b.z + a.w * b.w;
        }
        zcos[gi * B + j] = dot * inv_s[gi] * inv_s[j];
    } else if (tid == 0) {
        out[0] = 0.f;
    }
}

// ---------------------------------------------------------------------------
// K2 pair: one 2x2 row-tile per wave (4 pairs from 4 row-reads — halves L2
// traffic vs 1 pair/wave). 520 blocks x 256 threads (4 waves) = 2080 tiles
// exact. Diagonal tiles use weights {1,2,0,1}; off-diag weight 2 each —
// union over tiles reconstructs the full symmetric B^2 sum.
// ---------------------------------------------------------------------------
__global__ __launch_bounds__(256) void pair_kernel(const float* __restrict__ xs,
                                                   const float* __restrict__ zcos,
                                                   float* __restrict__ out) {
    __shared__ float mx[2];
    __shared__ float partial[4];
    int tid = threadIdx.x;

    // diagonal max of zcos (max attained on diagonal), 2 waves
    if (tid < B) {
        float v = zcos[tid * (B + 1)];
        #pragma unroll
        for (int o = 32; o > 0; o >>= 1) v = fmaxf(v, __shfl_down(v, o, 64));
        if ((tid & 63) == 0) mx[tid >> 6] = v;
    }
    __syncthreads();
    float maxv = fmaxf(mx[0], mx[1]);

    int w = tid >> 6;                  // wave 0..3
    int lane = tid & 63;
    int T = blockIdx.x * 4 + w;        // tile index, always < NTILE

    // decode T -> (ti, tj), ti<=tj over TROW=64 (validated decode pattern)
    float ff = (float)(2 * TROW + 1);
    int ti = (int)((ff - sqrtf(ff * ff - 8.0f * (float)T)) * 0.5f);
    if (ti < 0) ti = 0;
    if (ti > TROW - 1) ti = TROW - 1;
    while ((ti + 1) * TROW - ((ti + 1) * ti) / 2 <= T) ti++;
    while (ti * TROW - (ti * (ti - 1)) / 2 > T) ti--;
    int tj = ti + (T - (ti * TROW - (ti * (ti - 1)) / 2));

    int r0 = 2 * ti, r1 = r0 + 1;
    int c0 = 2 * tj, c1 = c0 + 1;

    const float4* a0 = (const float4*)(xs + (size_t)r0 * N);
    const float4* a1 = (const float4*)(xs + (size_t)r1 * N);
    const float4* b0 = (const float4*)(xs + (size_t)c0 * N);
    const float4* b1 = (const float4*)(xs + (size_t)c1 * N);

    float s00 = 0.f, s01 = 0.f, s10 = 0.f, s11 = 0.f;
    #pragma unroll
    for (int u = 0; u < N / 4 / 64; u++) {          // 12 iterations
        int idx = lane + u * 64;
        float4 va0 = a0[idx], va1 = a1[idx];
        float4 vb0 = b0[idx], vb1 = b1[idx];
        s00 += fabsf(va0.x - vb0.x) + fabsf(va0.y - vb0.y)
             + fabsf(va0.z - vb0.z) + fabsf(va0.w - vb0.w);
        s01 += fabsf(va0.x - vb1.x) + fabsf(va0.y - vb1.y)
             + fabsf(va0.z - vb1.z) + fabsf(va0.w - vb1.w);
        s10 += fabsf(va1.x - vb0.x) + fabsf(va1.y - vb0.y)
             + fabsf(va1.z - vb0.z) + fabsf(va1.w - vb0.w);
        s11 += fabsf(va1.x - vb1.x) + fabsf(va1.y - vb1.y)
             + fabsf(va1.z - vb1.z) + fabsf(va1.w - vb1.w);
    }
    #pragma unroll
    for (int o = 32; o > 0; o >>= 1) {
        s00 += __shfl_down(s00, o, 64);
        s01 += __shfl_down(s01, o, 64);
        s10 += __shfl_down(s10, o, 64);
        s11 += __shfl_down(s11, o, 64);
    }
    if (lane == 0) {
        bool diag = (ti == tj);
        float w00 = diag ? 1.0f : 2.0f;
        float w01 = 2.0f;
        float w10 = diag ? 0.0f : 2.0f;
        float w11 = diag ? 1.0f : 2.0f;
        float inv_n = 1.0f / N;
        float d00 = s00 * inv_n - (maxv - zcos[r0 * B + c0]);
        float d01 = s01 * inv_n - (maxv - zcos[r0 * B + c1]);
        float d10 = s10 * inv_n - (maxv - zcos[r1 * B + c0]);
        float d11 = s11 * inv_n - (maxv - zcos[r1 * B + c1]);
        partial[w] = w00 * d00 * d00 + w01 * d01 * d01
                   + w10 * d10 * d10 + w11 * d11 * d11;
    }
    __syncthreads();
    if (tid == 0) {
        float blk = partial[0] + partial[1] + partial[2] + partial[3];
        atomicAdd(out, blk * (1.0f / (B * B)));
    }
}

extern "C" void kernel_launch(void* const* d_in, const int* in_sizes, int n_in,
                              void* d_out, int out_size, void* d_ws, size_t ws_size,
                              hipStream_t stream) {
    const float* z = (const float*)d_in[0];   // [128,128]
    const float* x = (const float*)d_in[1];   // [128,3,32,32]
    float* out = (float*)d_out;               // [1]
    float* ws = (float*)d_ws;

    float* zcos = ws;                         // 16384 floats
    float* xs   = ws + 16384;                 // 393216 floats

    prep_kernel<<<B + NZBLK + 1, 1024, 0, stream>>>(x, z, xs, zcos, out);
    pair_kernel<<<PAIR_BLOCKS, 256, 0, stream>>>(xs, zcos, out);
}